// Round 7
// baseline (89.009 us; speedup 1.0000x reference)
//
#include <hip/hip_runtime.h>
#include <hip/hip_bf16.h>
#include <math.h>

// Problem constants (fixed by reference)
constexpr int Bsz = 4;
constexpr int SEQ = 2048;
constexpr int DM  = 512;
constexpr int NH  = 8;
constexpr int HD  = 64;      // DM / NH
constexpr int LAG = 10;      // MAX_LAG
constexpr int MROWS = Bsz * SEQ;                        // 8192
constexpr size_t OUT0_ELEMS = (size_t)Bsz * SEQ * DM;   // 4,194,304
constexpr int NQKV = 3 * DM;                            // 1536

typedef __attribute__((ext_vector_type(8))) short short8;
typedef __attribute__((ext_vector_type(4))) float f32x4;
typedef __attribute__((ext_vector_type(16))) float f32x16;

__device__ __forceinline__ float bf2f(unsigned short u) {
  union { unsigned int i; float f; } x; x.i = (unsigned int)u << 16; return x.f;
}
__device__ __forceinline__ unsigned short f2bf(float f) {
  __hip_bfloat16 h = __float2bfloat16(f);
  return *(unsigned short*)&h;
}

// ---------------------------------------------------------------------------
// async global -> LDS, 16B per lane. LDS dest is wave-uniform base + lane*16.
// ---------------------------------------------------------------------------
__device__ __forceinline__ void gload_lds16(const void* g, void* l) {
  __builtin_amdgcn_global_load_lds(
      (const __attribute__((address_space(1))) unsigned int*)g,
      (__attribute__((address_space(3))) unsigned int*)l, 16, 0, 0);
}

// ---------------------------------------------------------------------------
// Fused prep:
//   blocks [0,2048):    cast x f32->bf16 (8 elems/thread, vectorized)
//   blocks [2048,3072): transpose+cast weights
//   block  3072:        concatenate biases
//   blocks [3073,5121): zero-fill attn_out (64 MB, nontemporal) -- moved here
//                       from band_attn so the write burst overlaps prep reads.
// ---------------------------------------------------------------------------
__global__ __launch_bounds__(256) void prep(
    const float* __restrict__ x, const float* __restrict__ Wq,
    const float* __restrict__ Wk, const float* __restrict__ Wv,
    const float* __restrict__ Wo, const float* __restrict__ bq,
    const float* __restrict__ bk, const float* __restrict__ bv,
    __hip_bfloat16* __restrict__ xb, __hip_bfloat16* __restrict__ Wtqkv,
    __hip_bfloat16* __restrict__ Wot, float* __restrict__ bcat,
    float* __restrict__ attn_out) {
  __shared__ float t[32][33];
  const int blk = blockIdx.x;
  const int tid = threadIdx.x;
  if (blk < 2048) {
    // x cast, 8 elems/thread
    size_t i = ((size_t)blk * 256 + tid) * 8;
    float4 a = *(const float4*)(x + i);
    float4 b = *(const float4*)(x + i + 4);
    union { unsigned short h[8]; uint4 u; } pk;
    pk.h[0] = f2bf(a.x); pk.h[1] = f2bf(a.y); pk.h[2] = f2bf(a.z); pk.h[3] = f2bf(a.w);
    pk.h[4] = f2bf(b.x); pk.h[5] = f2bf(b.y); pk.h[6] = f2bf(b.z); pk.h[7] = f2bf(b.w);
    *(uint4*)(xb + i) = pk.u;
  } else if (blk < 3072) {
    const int zb = blk - 2048;
    const int z = zb >> 8, rem = zb & 255;
    const float* W = (z == 0) ? Wq : (z == 1) ? Wk : (z == 2) ? Wv : Wo;
    __hip_bfloat16* dst = (z < 3) ? (Wtqkv + (size_t)z * DM * DM) : Wot;
    const int n0 = (rem & 15) * 32, k0 = (rem >> 4) * 32;
    const int tx = tid & 31, ty = tid >> 5;
#pragma unroll
    for (int r = 0; r < 4; r++)
      t[ty + r * 8][tx] = W[(size_t)(k0 + ty + r * 8) * DM + n0 + tx];
    __syncthreads();
#pragma unroll
    for (int r = 0; r < 4; r++)
      dst[(size_t)(n0 + ty + r * 8) * DM + k0 + tx] =
          __float2bfloat16(t[tx][ty + r * 8]);
  } else if (blk == 3072) {
    for (int i = tid; i < NQKV; i += 256)
      bcat[i] = (i < 512) ? bq[i] : (i < 1024) ? bk[i - 512] : bv[i - 1024];
  } else {
    // attn_out zero-fill: 2048 blocks x 32 KB each
    const int f = blk - 3073;
    f32x4* base = (f32x4*)(attn_out + (size_t)f * 8192);
    f32x4 z = {0.f, 0.f, 0.f, 0.f};
#pragma unroll
    for (int t8 = 0; t8 < 8; ++t8)
      __builtin_nontemporal_store(z, base + t8 * 256 + tid);
  }
}

// ---------------------------------------------------------------------------
// bf16 MFMA GEMM: C[M,N] = A[M,K] @ Bt[N,K]^T + bias[N]
// 128x128 tile, BK=64, 4 waves (2x2), 32x32x16 MFMA, m97 structure.
// T2-style XOR swizzle via pre-swizzled SOURCE + swizzled ds_read (rule #21).
// T1 XCD-aware block swizzle (grid % 8 == 0).
// Epilogue staged through LDS (aliased over As/Bs) for coalesced stores.
// (r4 structure -- best measured; r6's A-f32 reg-staging reverted, m151.)
// ---------------------------------------------------------------------------
template <bool OUT_BF16>
__global__ __launch_bounds__(256) void gemm_mfma(
    const __hip_bfloat16* __restrict__ A, const __hip_bfloat16* __restrict__ Bt,
    const float* __restrict__ bias, void* __restrict__ Cout,
    int N, int K, int gx) {
  __shared__ __align__(16) char smem[32768];
  unsigned short (*As)[64] = (unsigned short (*)[64])smem;            // [128][64]
  unsigned short (*Bs)[64] = (unsigned short (*)[64])(smem + 16384);  // [128][64]

  // XCD-aware bijective swizzle
  int lin = blockIdx.x;
  const int cpx = gridDim.x >> 3;
  lin = (lin & 7) * cpx + (lin >> 3);
  const int bm = (lin / gx) * 128;
  const int bn = (lin % gx) * 128;

  const int tid = threadIdx.x;
  const int lane = tid & 63, wave = tid >> 6;
  const int wr = wave >> 1, wc = wave & 1;
  const int l31 = lane & 31, lhi = lane >> 5;

  f32x16 acc[2][2] = {};

  for (int k0 = 0; k0 < K; k0 += 64) {
#pragma unroll
    for (int it = 0; it < 4; ++it) {
      const int g = it * 256 + tid;
      const int row = g >> 3, ch = g & 7;
      const int src_ch = ch ^ (row & 7);  // inverse swizzle on SOURCE
      gload_lds16(A + (size_t)(bm + row) * K + k0 + src_ch * 8,
                  (char*)As + (it * 256 + wave * 64) * 16);
    }
#pragma unroll
    for (int it = 0; it < 4; ++it) {
      const int g = it * 256 + tid;
      const int row = g >> 3, ch = g & 7;
      const int src_ch = ch ^ (row & 7);
      gload_lds16(Bt + (size_t)(bn + row) * K + k0 + src_ch * 8,
                  (char*)Bs + (it * 256 + wave * 64) * 16);
    }
    __syncthreads();

#pragma unroll
    for (int kk = 0; kk < 4; ++kk) {   // 4 x K=16 sub-steps
      short8 a[2], b[2];
#pragma unroll
      for (int fi = 0; fi < 2; ++fi) {
        const int row = wr * 64 + fi * 32 + l31;
        const int ch = (kk * 2 + lhi) ^ (row & 7);  // swizzled read
        a[fi] = *(const short8*)((const char*)As + row * 128 + ch * 16);
      }
#pragma unroll
      for (int fj = 0; fj < 2; ++fj) {
        const int row = wc * 64 + fj * 32 + l31;
        const int ch = (kk * 2 + lhi) ^ (row & 7);
        b[fj] = *(const short8*)((const char*)Bs + row * 128 + ch * 16);
      }
#pragma unroll
      for (int fi = 0; fi < 2; ++fi)
#pragma unroll
        for (int fj = 0; fj < 2; ++fj)
          acc[fi][fj] = __builtin_amdgcn_mfma_f32_32x32x16_bf16(
              a[fi], b[fj], acc[fi][fj], 0, 0, 0);
    }
    __syncthreads();
  }

  // Epilogue staged through LDS (alias over As/Bs; safe after final barrier).
  // C/D layout: col = lane&31, row = (reg&3) + 8*(reg>>2) + 4*(lane>>5).
  if (OUT_BF16) {
    unsigned short (*Cs)[128] = (unsigned short (*)[128])smem;  // 32 KB
#pragma unroll
    for (int fj = 0; fj < 2; ++fj) {
      const float bv = bias[bn + wc * 64 + fj * 32 + l31];
      const int col = wc * 64 + fj * 32 + l31;
#pragma unroll
      for (int fi = 0; fi < 2; ++fi)
#pragma unroll
        for (int r = 0; r < 16; ++r) {
          const int row = wr * 64 + fi * 32 + (r & 3) + 8 * (r >> 2) + 4 * lhi;
          Cs[row][col] = f2bf(acc[fi][fj][r] + bv);
        }
    }
    __syncthreads();
    __hip_bfloat16* C = (__hip_bfloat16*)Cout;
#pragma unroll
    for (int t = 0; t < 8; ++t) {
      const int g = t * 256 + tid;      // 2048 x 16B chunks
      const int row = g >> 4, ch = g & 15;
      *(uint4*)(C + (size_t)(bm + row) * N + bn + ch * 8) =
          *(const uint4*)&Cs[row][ch * 8];
    }
  } else {
    float (*Cs)[128] = (float (*)[128])smem;  // 32 KB = 64 rows
    float* C = (float*)Cout;
#pragma unroll
    for (int half = 0; half < 2; ++half) {
      if (wr == half) {
#pragma unroll
        for (int fj = 0; fj < 2; ++fj) {
          const float bv = bias[bn + wc * 64 + fj * 32 + l31];
          const int col = wc * 64 + fj * 32 + l31;
#pragma unroll
          for (int fi = 0; fi < 2; ++fi)
#pragma unroll
            for (int r = 0; r < 16; ++r) {
              const int row = fi * 32 + (r & 3) + 8 * (r >> 2) + 4 * lhi;  // 0..63
              Cs[row][col] = acc[fi][fj][r] + bv;
            }
        }
      }
      __syncthreads();
#pragma unroll
      for (int t = 0; t < 8; ++t) {
        const int g = t * 256 + tid;    // 2048 x float4 chunks
        const int row = g >> 5, ch = g & 31;
        *(float4*)(C + (size_t)(bm + half * 64 + row) * N + bn + ch * 4) =
            *(const float4*)&Cs[row][ch * 4];
      }
      __syncthreads();
    }
  }
}

// ---------------------------------------------------------------------------
// Banded causal attention (band width LAG+1 = 11; off-band probs exactly 0).
// One block per (b,i) row; h = tid>>5, lane = tid&31; lane covers head-dims
// {2*lane, 2*lane+1}. attn_out was pre-zeroed in prep -- this kernel writes
// ONLY the <=11 band entries per row (nontemporal) + the ctx row.
// ---------------------------------------------------------------------------
__global__ __launch_bounds__(256) void band_attn(
    const __hip_bfloat16* __restrict__ qkv, const float* __restrict__ decay_p,
    __hip_bfloat16* __restrict__ ctx, float* __restrict__ attn_out) {
  const int bi = blockIdx.x;
  const int b = bi >> 11;
  const int i = bi & (SEQ - 1);
  const int tid = threadIdx.x;
  const int h = tid >> 5;
  const int lane = tid & 31;

  __shared__ float dlds[LAG + 1];
  __shared__ float att_h[NH][LAG + 2];

  if (tid <= LAG) {
    float p = decay_p[tid];
    float sp = fmaxf(p, 0.0f) + log1pf(expf(-fabsf(p)));  // stable softplus
    dlds[tid] = -logf(sp + 1e-8f);
  }
  __syncthreads();

  const int jlo = (i >= LAG) ? (i - LAG) : 0;
  const int nj = i - jlo + 1;

  const unsigned int qu = *(const unsigned int*)(
      (const unsigned short*)(qkv + (size_t)bi * NQKV + h * HD) + 2 * lane);
  const float q0 = bf2f((unsigned short)qu);
  const float q1 = bf2f((unsigned short)(qu >> 16));

  float s[LAG + 1];
#pragma unroll
  for (int jj = 0; jj <= LAG; jj++) {
    const int j = jlo + jj;
    const bool ok = (j <= i);
    const int jc = ok ? j : i;
    const unsigned int ku = *(const unsigned int*)(
        (const unsigned short*)(qkv + ((size_t)b * SEQ + jc) * NQKV + DM + h * HD) +
        2 * lane);
    float part = q0 * bf2f((unsigned short)ku) +
                 q1 * bf2f((unsigned short)(ku >> 16));
#pragma unroll
    for (int m = 16; m >= 1; m >>= 1) part += __shfl_xor(part, m, 32);
    s[jj] = ok ? (part * 0.125f + dlds[i - j]) : -1e30f;
  }

  float mx = -1e30f;
#pragma unroll
  for (int jj = 0; jj <= LAG; jj++) mx = fmaxf(mx, s[jj]);
  float sum = 0.0f;
#pragma unroll
  for (int jj = 0; jj <= LAG; jj++) { s[jj] = expf(s[jj] - mx); sum += s[jj]; }
  const float inv = 1.0f / sum;

  float c0 = 0.0f, c1 = 0.0f;
#pragma unroll
  for (int jj = 0; jj <= LAG; jj++) {
    const float p = s[jj] * inv;
    const int jc = (jlo + jj <= i) ? (jlo + jj) : i;
    const unsigned int vu = *(const unsigned int*)(
        (const unsigned short*)(qkv + ((size_t)b * SEQ + jc) * NQKV + 2 * DM + h * HD) +
        2 * lane);
    c0 += p * bf2f((unsigned short)vu);
    c1 += p * bf2f((unsigned short)(vu >> 16));
    if (lane == 0) att_h[h][jj] = p;
  }
  const unsigned int pk =
      ((unsigned int)f2bf(c1) << 16) | (unsigned int)f2bf(c0);
  *(unsigned int*)((unsigned short*)(ctx + (size_t)bi * DM + h * HD) + 2 * lane) = pk;
  __syncthreads();

  // band write only (row pre-zeroed in prep)
  if (tid < nj) {
    float a = 0.0f;
#pragma unroll
    for (int hh = 0; hh < NH; hh++) a += att_h[hh][tid];
    __builtin_nontemporal_store(a * (1.0f / NH),
                                attn_out + (size_t)bi * SEQ + jlo + tid);
  }
}

// ---------------------------------------------------------------------------
extern "C" void kernel_launch(void* const* d_in, const int* in_sizes, int n_in,
                              void* d_out, int out_size, void* d_ws, size_t ws_size,
                              hipStream_t stream) {
  const float* x   = (const float*)d_in[0];
  const float* Wq  = (const float*)d_in[1];
  const float* bq  = (const float*)d_in[2];
  const float* Wk  = (const float*)d_in[3];
  const float* bk  = (const float*)d_in[4];
  const float* Wv  = (const float*)d_in[5];
  const float* bv  = (const float*)d_in[6];
  const float* Wo  = (const float*)d_in[7];
  const float* bo  = (const float*)d_in[8];
  const float* dec = (const float*)d_in[9];

  float* out      = (float*)d_out;                 // [B,S,D]
  float* attn_out = out + OUT0_ELEMS;              // [B,S,S]

  // Workspace layout (16B-aligned), ~44 MB
  char* w = (char*)d_ws;
  __hip_bfloat16* xb    = (__hip_bfloat16*)w;  w += (size_t)MROWS * DM * 2;
  __hip_bfloat16* Wtqkv = (__hip_bfloat16*)w;  w += (size_t)NQKV * DM * 2;
  __hip_bfloat16* Wot   = (__hip_bfloat16*)w;  w += (size_t)DM * DM * 2;
  float*          bcat  = (float*)w;           w += (size_t)NQKV * 4;
  __hip_bfloat16* qkv   = (__hip_bfloat16*)w;  w += (size_t)MROWS * NQKV * 2;
  __hip_bfloat16* ctxb  = (__hip_bfloat16*)w;

  prep<<<5121, 256, 0, stream>>>(x, Wq, Wk, Wv, Wo, bq, bk, bv,
                                 xb, Wtqkv, Wot, bcat, attn_out);

  // Fused QKV projection: [8192,512] @ [512,1536] -> bf16 qkv
  gemm_mfma<true><<<768, 256, 0, stream>>>(xb, Wtqkv, bcat, qkv,
                                           NQKV, DM, NQKV / 128);

  band_attn<<<MROWS, 256, 0, stream>>>(qkv, dec, ctxb, attn_out);

  // Output projection: [8192,512] @ [512,512] -> f32 out
  gemm_mfma<false><<<256, 256, 0, stream>>>(ctxb, Wot, bo, out,
                                            DM, DM, DM / 128);
}

// Round 8
// 83.944 us; speedup vs baseline: 1.0603x; 1.0603x over previous
//
#include <hip/hip_runtime.h>
#include <hip/hip_bf16.h>
#include <math.h>

// Problem constants (fixed by reference)
constexpr int Bsz = 4;
constexpr int SEQ = 2048;
constexpr int DM  = 512;
constexpr int NH  = 8;
constexpr int HD  = 64;      // DM / NH
constexpr int LAG = 10;      // MAX_LAG
constexpr int MROWS = Bsz * SEQ;                        // 8192
constexpr size_t OUT0_ELEMS = (size_t)Bsz * SEQ * DM;   // 4,194,304
constexpr int NQKV = 3 * DM;                            // 1536
constexpr int ATTN_V4 = Bsz * SEQ * SEQ / 4;            // 4,194,304 float4s

typedef __attribute__((ext_vector_type(8))) short short8;
typedef __attribute__((ext_vector_type(4))) float f32x4;
typedef __attribute__((ext_vector_type(16))) float f32x16;

__device__ __forceinline__ float bf2f(unsigned short u) {
  union { unsigned int i; float f; } x; x.i = (unsigned int)u << 16; return x.f;
}
__device__ __forceinline__ unsigned short f2bf(float f) {
  __hip_bfloat16 h = __float2bfloat16(f);
  return *(unsigned short*)&h;
}

// ---------------------------------------------------------------------------
// async global -> LDS, 16B per lane. LDS dest is wave-uniform base + lane*16.
// ---------------------------------------------------------------------------
__device__ __forceinline__ void gload_lds16(const void* g, void* l) {
  __builtin_amdgcn_global_load_lds(
      (const __attribute__((address_space(1))) unsigned int*)g,
      (__attribute__((address_space(3))) unsigned int*)l, 16, 0, 0);
}

// ---------------------------------------------------------------------------
// Fused prep (r4 structure): blocks [0,2048) cast x f32->bf16;
// [2048,3072) transpose+cast weights; block 3072 concatenates biases.
// ---------------------------------------------------------------------------
__global__ __launch_bounds__(256) void prep(
    const float* __restrict__ x, const float* __restrict__ Wq,
    const float* __restrict__ Wk, const float* __restrict__ Wv,
    const float* __restrict__ Wo, const float* __restrict__ bq,
    const float* __restrict__ bk, const float* __restrict__ bv,
    __hip_bfloat16* __restrict__ xb, __hip_bfloat16* __restrict__ Wtqkv,
    __hip_bfloat16* __restrict__ Wot, float* __restrict__ bcat) {
  __shared__ float t[32][33];
  const int blk = blockIdx.x;
  const int tid = threadIdx.x;
  if (blk < 2048) {
    // x cast, 8 elems/thread
    size_t i = ((size_t)blk * 256 + tid) * 8;
    float4 a = *(const float4*)(x + i);
    float4 b = *(const float4*)(x + i + 4);
    union { unsigned short h[8]; uint4 u; } pk;
    pk.h[0] = f2bf(a.x); pk.h[1] = f2bf(a.y); pk.h[2] = f2bf(a.z); pk.h[3] = f2bf(a.w);
    pk.h[4] = f2bf(b.x); pk.h[5] = f2bf(b.y); pk.h[6] = f2bf(b.z); pk.h[7] = f2bf(b.w);
    *(uint4*)(xb + i) = pk.u;
  } else if (blk < 3072) {
    const int zb = blk - 2048;
    const int z = zb >> 8, rem = zb & 255;
    const float* W = (z == 0) ? Wq : (z == 1) ? Wk : (z == 2) ? Wv : Wo;
    __hip_bfloat16* dst = (z < 3) ? (Wtqkv + (size_t)z * DM * DM) : Wot;
    const int n0 = (rem & 15) * 32, k0 = (rem >> 4) * 32;
    const int tx = tid & 31, ty = tid >> 5;
#pragma unroll
    for (int r = 0; r < 4; r++)
      t[ty + r * 8][tx] = W[(size_t)(k0 + ty + r * 8) * DM + n0 + tx];
    __syncthreads();
#pragma unroll
    for (int r = 0; r < 4; r++)
      dst[(size_t)(n0 + ty + r * 8) * DM + k0 + tx] =
          __float2bfloat16(t[tx][ty + r * 8]);
  } else {
    for (int i = tid; i < NQKV; i += 256)
      bcat[i] = (i < 512) ? bq[i] : (i < 1024) ? bk[i - 512] : bv[i - 1024];
  }
}

// ---------------------------------------------------------------------------
// bf16 MFMA GEMM: C[M,N] = A[M,K] @ Bt[N,K]^T + bias[N]   (r4 structure)
// 128x128 tile, BK=64, 4 waves (2x2), 32x32x16 MFMA, m97 staging.
// T2-style XOR swizzle via pre-swizzled SOURCE + swizzled ds_read (rule #21).
// T1 XCD-aware block swizzle (grid % 8 == 0).
// Epilogue staged through LDS for coalesced stores.
// NEW: optional attn_out zero-fill piggybacked on the K-loop -- 3 nontemporal
// float4 stores per thread per K-step, issued after the staging barrier so
// they drain during the compute phase (rides idle write BW of this
// LDS/MFMA-bound kernel; removes the 64 MB fill burst from band_attn).
// ---------------------------------------------------------------------------
template <bool OUT_BF16>
__global__ __launch_bounds__(256) void gemm_mfma(
    const __hip_bfloat16* __restrict__ A, const __hip_bfloat16* __restrict__ Bt,
    const float* __restrict__ bias, void* __restrict__ Cout,
    int N, int K, int gx, float* __restrict__ fill) {
  __shared__ __align__(16) char smem[32768];
  unsigned short (*As)[64] = (unsigned short (*)[64])smem;            // [128][64]
  unsigned short (*Bs)[64] = (unsigned short (*)[64])(smem + 16384);  // [128][64]

  // XCD-aware bijective swizzle
  int lin = blockIdx.x;
  const int cpx = gridDim.x >> 3;
  lin = (lin & 7) * cpx + (lin >> 3);
  const int bm = (lin / gx) * 128;
  const int bn = (lin % gx) * 128;

  const int tid = threadIdx.x;
  const int lane = tid & 63, wave = tid >> 6;
  const int wr = wave >> 1, wc = wave & 1;
  const int l31 = lane & 31, lhi = lane >> 5;
  const int gtid = blockIdx.x * 256 + tid;
  const int gstride = gridDim.x << 8;

  f32x16 acc[2][2] = {};

  for (int k0 = 0; k0 < K; k0 += 64) {
#pragma unroll
    for (int it = 0; it < 4; ++it) {
      const int g = it * 256 + tid;
      const int row = g >> 3, ch = g & 7;
      const int src_ch = ch ^ (row & 7);  // inverse swizzle on SOURCE
      gload_lds16(A + (size_t)(bm + row) * K + k0 + src_ch * 8,
                  (char*)As + (it * 256 + wave * 64) * 16);
    }
#pragma unroll
    for (int it = 0; it < 4; ++it) {
      const int g = it * 256 + tid;
      const int row = g >> 3, ch = g & 7;
      const int src_ch = ch ^ (row & 7);
      gload_lds16(Bt + (size_t)(bn + row) * K + k0 + src_ch * 8,
                  (char*)Bs + (it * 256 + wave * 64) * 16);
    }
    __syncthreads();   // vmcnt(0) drain (staging + previous step's fill)

    // Piggybacked attn_out zero-fill: issued now, drains during compute.
    if (fill != nullptr) {
      const int step = k0 >> 6;
      f32x4 z = {0.f, 0.f, 0.f, 0.f};
#pragma unroll
      for (int j = 0; j < 3; ++j) {
        const int idx = gtid + (step * 3 + j) * gstride;
        if (idx < ATTN_V4)
          __builtin_nontemporal_store(z, (f32x4*)fill + idx);
      }
    }

#pragma unroll
    for (int kk = 0; kk < 4; ++kk) {   // 4 x K=16 sub-steps
      short8 a[2], b[2];
#pragma unroll
      for (int fi = 0; fi < 2; ++fi) {
        const int row = wr * 64 + fi * 32 + l31;
        const int ch = (kk * 2 + lhi) ^ (row & 7);  // swizzled read
        a[fi] = *(const short8*)((const char*)As + row * 128 + ch * 16);
      }
#pragma unroll
      for (int fj = 0; fj < 2; ++fj) {
        const int row = wc * 64 + fj * 32 + l31;
        const int ch = (kk * 2 + lhi) ^ (row & 7);
        b[fj] = *(const short8*)((const char*)Bs + row * 128 + ch * 16);
      }
#pragma unroll
      for (int fi = 0; fi < 2; ++fi)
#pragma unroll
        for (int fj = 0; fj < 2; ++fj)
          acc[fi][fj] = __builtin_amdgcn_mfma_f32_32x32x16_bf16(
              a[fi], b[fj], acc[fi][fj], 0, 0, 0);
    }
    __syncthreads();
  }

  // Epilogue staged through LDS (alias over As/Bs; safe after final barrier).
  // C/D layout: col = lane&31, row = (reg&3) + 8*(reg>>2) + 4*(lane>>5).
  if (OUT_BF16) {
    unsigned short (*Cs)[128] = (unsigned short (*)[128])smem;  // 32 KB
#pragma unroll
    for (int fj = 0; fj < 2; ++fj) {
      const float bv = bias[bn + wc * 64 + fj * 32 + l31];
      const int col = wc * 64 + fj * 32 + l31;
#pragma unroll
      for (int fi = 0; fi < 2; ++fi)
#pragma unroll
        for (int r = 0; r < 16; ++r) {
          const int row = wr * 64 + fi * 32 + (r & 3) + 8 * (r >> 2) + 4 * lhi;
          Cs[row][col] = f2bf(acc[fi][fj][r] + bv);
        }
    }
    __syncthreads();
    __hip_bfloat16* C = (__hip_bfloat16*)Cout;
#pragma unroll
    for (int t = 0; t < 8; ++t) {
      const int g = t * 256 + tid;      // 2048 x 16B chunks
      const int row = g >> 4, ch = g & 15;
      *(uint4*)(C + (size_t)(bm + row) * N + bn + ch * 8) =
          *(const uint4*)&Cs[row][ch * 8];
    }
  } else {
    float (*Cs)[128] = (float (*)[128])smem;  // 32 KB = 64 rows
    float* C = (float*)Cout;
#pragma unroll
    for (int half = 0; half < 2; ++half) {
      if (wr == half) {
#pragma unroll
        for (int fj = 0; fj < 2; ++fj) {
          const float bv = bias[bn + wc * 64 + fj * 32 + l31];
          const int col = wc * 64 + fj * 32 + l31;
#pragma unroll
          for (int fi = 0; fi < 2; ++fi)
#pragma unroll
            for (int r = 0; r < 16; ++r) {
              const int row = fi * 32 + (r & 3) + 8 * (r >> 2) + 4 * lhi;  // 0..63
              Cs[row][col] = acc[fi][fj][r] + bv;
            }
        }
      }
      __syncthreads();
#pragma unroll
      for (int t = 0; t < 8; ++t) {
        const int g = t * 256 + tid;    // 2048 x float4 chunks
        const int row = g >> 5, ch = g & 31;
        *(float4*)(C + (size_t)(bm + half * 64 + row) * N + bn + ch * 4) =
            *(const float4*)&Cs[row][ch * 4];
      }
      __syncthreads();
    }
  }
}

// ---------------------------------------------------------------------------
// Banded causal attention (band width LAG+1 = 11; off-band probs exactly 0).
// One block per (b,i) row (r4 best config); h = tid>>5, lane = tid&31; lane
// covers head-dims {2*lane, 2*lane+1}. attn_out was pre-zeroed by the QKV
// GEMM's piggybacked fill -- this kernel writes ONLY the <=11 band entries
// per row (nontemporal) + the ctx row.
// ---------------------------------------------------------------------------
__global__ __launch_bounds__(256) void band_attn(
    const __hip_bfloat16* __restrict__ qkv, const float* __restrict__ decay_p,
    __hip_bfloat16* __restrict__ ctx, float* __restrict__ attn_out) {
  const int bi = blockIdx.x;
  const int b = bi >> 11;
  const int i = bi & (SEQ - 1);
  const int tid = threadIdx.x;
  const int h = tid >> 5;
  const int lane = tid & 31;

  __shared__ float dlds[LAG + 1];
  __shared__ float att_h[NH][LAG + 2];

  if (tid <= LAG) {
    float p = decay_p[tid];
    float sp = fmaxf(p, 0.0f) + log1pf(expf(-fabsf(p)));  // stable softplus
    dlds[tid] = -logf(sp + 1e-8f);
  }
  __syncthreads();

  const int jlo = (i >= LAG) ? (i - LAG) : 0;
  const int nj = i - jlo + 1;

  const unsigned int qu = *(const unsigned int*)(
      (const unsigned short*)(qkv + (size_t)bi * NQKV + h * HD) + 2 * lane);
  const float q0 = bf2f((unsigned short)qu);
  const float q1 = bf2f((unsigned short)(qu >> 16));

  float s[LAG + 1];
#pragma unroll
  for (int jj = 0; jj <= LAG; jj++) {
    const int j = jlo + jj;
    const bool ok = (j <= i);
    const int jc = ok ? j : i;
    const unsigned int ku = *(const unsigned int*)(
        (const unsigned short*)(qkv + ((size_t)b * SEQ + jc) * NQKV + DM + h * HD) +
        2 * lane);
    float part = q0 * bf2f((unsigned short)ku) +
                 q1 * bf2f((unsigned short)(ku >> 16));
#pragma unroll
    for (int m = 16; m >= 1; m >>= 1) part += __shfl_xor(part, m, 32);
    s[jj] = ok ? (part * 0.125f + dlds[i - j]) : -1e30f;
  }

  float mx = -1e30f;
#pragma unroll
  for (int jj = 0; jj <= LAG; jj++) mx = fmaxf(mx, s[jj]);
  float sum = 0.0f;
#pragma unroll
  for (int jj = 0; jj <= LAG; jj++) { s[jj] = expf(s[jj] - mx); sum += s[jj]; }
  const float inv = 1.0f / sum;

  float c0 = 0.0f, c1 = 0.0f;
#pragma unroll
  for (int jj = 0; jj <= LAG; jj++) {
    const float p = s[jj] * inv;
    const int jc = (jlo + jj <= i) ? (jlo + jj) : i;
    const unsigned int vu = *(const unsigned int*)(
        (const unsigned short*)(qkv + ((size_t)b * SEQ + jc) * NQKV + 2 * DM + h * HD) +
        2 * lane);
    c0 += p * bf2f((unsigned short)vu);
    c1 += p * bf2f((unsigned short)(vu >> 16));
    if (lane == 0) att_h[h][jj] = p;
  }
  const unsigned int pk =
      ((unsigned int)f2bf(c1) << 16) | (unsigned int)f2bf(c0);
  *(unsigned int*)((unsigned short*)(ctx + (size_t)bi * DM + h * HD) + 2 * lane) = pk;
  __syncthreads();

  // band write only (row pre-zeroed by QKV GEMM's fill)
  if (tid < nj) {
    float a = 0.0f;
#pragma unroll
    for (int hh = 0; hh < NH; hh++) a += att_h[hh][tid];
    __builtin_nontemporal_store(a * (1.0f / NH),
                                attn_out + (size_t)bi * SEQ + jlo + tid);
  }
}

// ---------------------------------------------------------------------------
extern "C" void kernel_launch(void* const* d_in, const int* in_sizes, int n_in,
                              void* d_out, int out_size, void* d_ws, size_t ws_size,
                              hipStream_t stream) {
  const float* x   = (const float*)d_in[0];
  const float* Wq  = (const float*)d_in[1];
  const float* bq  = (const float*)d_in[2];
  const float* Wk  = (const float*)d_in[3];
  const float* bk  = (const float*)d_in[4];
  const float* Wv  = (const float*)d_in[5];
  const float* bv  = (const float*)d_in[6];
  const float* Wo  = (const float*)d_in[7];
  const float* bo  = (const float*)d_in[8];
  const float* dec = (const float*)d_in[9];

  float* out      = (float*)d_out;                 // [B,S,D]
  float* attn_out = out + OUT0_ELEMS;              // [B,S,S]

  // Workspace layout (16B-aligned), ~44 MB
  char* w = (char*)d_ws;
  __hip_bfloat16* xb    = (__hip_bfloat16*)w;  w += (size_t)MROWS * DM * 2;
  __hip_bfloat16* Wtqkv = (__hip_bfloat16*)w;  w += (size_t)NQKV * DM * 2;
  __hip_bfloat16* Wot   = (__hip_bfloat16*)w;  w += (size_t)DM * DM * 2;
  float*          bcat  = (float*)w;           w += (size_t)NQKV * 4;
  __hip_bfloat16* qkv   = (__hip_bfloat16*)w;  w += (size_t)MROWS * NQKV * 2;
  __hip_bfloat16* ctxb  = (__hip_bfloat16*)w;

  prep<<<3073, 256, 0, stream>>>(x, Wq, Wk, Wv, Wo, bq, bk, bv,
                                 xb, Wtqkv, Wot, bcat);

  // Fused QKV projection (+ piggybacked attn_out zero-fill)
  gemm_mfma<true><<<768, 256, 0, stream>>>(xb, Wtqkv, bcat, qkv,
                                           NQKV, DM, NQKV / 128, attn_out);

  band_attn<<<MROWS, 256, 0, stream>>>(qkv, dec, ctxb, attn_out);

  // Output projection: [8192,512] @ [512,512] -> f32 out
  gemm_mfma<false><<<256, 256, 0, stream>>>(ctxb, Wot, bo, out,
                                            DM, DM, DM / 128, nullptr);
}

// Round 9
// 80.940 us; speedup vs baseline: 1.0997x; 1.0371x over previous
//
#include <hip/hip_runtime.h>
#include <hip/hip_bf16.h>
#include <math.h>

// Problem constants (fixed by reference)
constexpr int Bsz = 4;
constexpr int SEQ = 2048;
constexpr int DM  = 512;
constexpr int NH  = 8;
constexpr int HD  = 64;      // DM / NH
constexpr int LAG = 10;      // MAX_LAG
constexpr int MROWS = Bsz * SEQ;                        // 8192
constexpr size_t OUT0_ELEMS = (size_t)Bsz * SEQ * DM;   // 4,194,304
constexpr int NQKV = 3 * DM;                            // 1536
constexpr int ATTN_V4 = Bsz * SEQ * SEQ / 4;            // 4,194,304 float4s

typedef __attribute__((ext_vector_type(8))) short short8;
typedef __attribute__((ext_vector_type(4))) float f32x4;
typedef __attribute__((ext_vector_type(16))) float f32x16;

__device__ __forceinline__ float bf2f(unsigned short u) {
  union { unsigned int i; float f; } x; x.i = (unsigned int)u << 16; return x.f;
}
__device__ __forceinline__ unsigned short f2bf(float f) {
  __hip_bfloat16 h = __float2bfloat16(f);
  return *(unsigned short*)&h;
}

// ---------------------------------------------------------------------------
// async global -> LDS, 16B per lane. LDS dest is wave-uniform base + lane*16.
// ---------------------------------------------------------------------------
__device__ __forceinline__ void gload_lds16(const void* g, void* l) {
  __builtin_amdgcn_global_load_lds(
      (const __attribute__((address_space(1))) unsigned int*)g,
      (__attribute__((address_space(3))) unsigned int*)l, 16, 0, 0);
}

// ---------------------------------------------------------------------------
// Fused prep: blocks [0,2048) cast x f32->bf16; [2048,3072) transpose+cast
// weights; block 3072 concatenates biases.
// ---------------------------------------------------------------------------
__global__ __launch_bounds__(256) void prep(
    const float* __restrict__ x, const float* __restrict__ Wq,
    const float* __restrict__ Wk, const float* __restrict__ Wv,
    const float* __restrict__ Wo, const float* __restrict__ bq,
    const float* __restrict__ bk, const float* __restrict__ bv,
    __hip_bfloat16* __restrict__ xb, __hip_bfloat16* __restrict__ Wtqkv,
    __hip_bfloat16* __restrict__ Wot, float* __restrict__ bcat) {
  __shared__ float t[32][33];
  const int blk = blockIdx.x;
  const int tid = threadIdx.x;
  if (blk < 2048) {
    // x cast, 8 elems/thread
    size_t i = ((size_t)blk * 256 + tid) * 8;
    float4 a = *(const float4*)(x + i);
    float4 b = *(const float4*)(x + i + 4);
    union { unsigned short h[8]; uint4 u; } pk;
    pk.h[0] = f2bf(a.x); pk.h[1] = f2bf(a.y); pk.h[2] = f2bf(a.z); pk.h[3] = f2bf(a.w);
    pk.h[4] = f2bf(b.x); pk.h[5] = f2bf(b.y); pk.h[6] = f2bf(b.z); pk.h[7] = f2bf(b.w);
    *(uint4*)(xb + i) = pk.u;
  } else if (blk < 3072) {
    const int zb = blk - 2048;
    const int z = zb >> 8, rem = zb & 255;
    const float* W = (z == 0) ? Wq : (z == 1) ? Wk : (z == 2) ? Wv : Wo;
    __hip_bfloat16* dst = (z < 3) ? (Wtqkv + (size_t)z * DM * DM) : Wot;
    const int n0 = (rem & 15) * 32, k0 = (rem >> 4) * 32;
    const int tx = tid & 31, ty = tid >> 5;
#pragma unroll
    for (int r = 0; r < 4; r++)
      t[ty + r * 8][tx] = W[(size_t)(k0 + ty + r * 8) * DM + n0 + tx];
    __syncthreads();
#pragma unroll
    for (int r = 0; r < 4; r++)
      dst[(size_t)(n0 + ty + r * 8) * DM + k0 + tx] =
          __float2bfloat16(t[tx][ty + r * 8]);
  } else {
    for (int i = tid; i < NQKV; i += 256)
      bcat[i] = (i < 512) ? bq[i] : (i < 1024) ? bk[i - 512] : bv[i - 1024];
  }
}

// ---------------------------------------------------------------------------
// bf16 MFMA GEMM: C[M,N] = A[M,K] @ Bt[N,K]^T + bias[N]   (r4 structure)
// 128x128 tile, BK=64, 4 waves (2x2), 32x32x16 MFMA, m97 staging.
// T2-style XOR swizzle via pre-swizzled SOURCE + swizzled ds_read (rule #21).
// T1 XCD-aware block swizzle (grid % 8 == 0): XCD x owns M-rows
// [x*M/8,(x+1)*M/8) -- matched by band_attn's affine mapping below.
// Epilogue staged through LDS for coalesced stores.
// Optional attn_out zero-fill piggybacked on the K-loop (drains under MFMA).
// ---------------------------------------------------------------------------
template <bool OUT_BF16>
__global__ __launch_bounds__(256) void gemm_mfma(
    const __hip_bfloat16* __restrict__ A, const __hip_bfloat16* __restrict__ Bt,
    const float* __restrict__ bias, void* __restrict__ Cout,
    int N, int K, int gx, float* __restrict__ fill) {
  __shared__ __align__(16) char smem[32768];
  unsigned short (*As)[64] = (unsigned short (*)[64])smem;            // [128][64]
  unsigned short (*Bs)[64] = (unsigned short (*)[64])(smem + 16384);  // [128][64]

  // XCD-aware bijective swizzle
  int lin = blockIdx.x;
  const int cpx = gridDim.x >> 3;
  lin = (lin & 7) * cpx + (lin >> 3);
  const int bm = (lin / gx) * 128;
  const int bn = (lin % gx) * 128;

  const int tid = threadIdx.x;
  const int lane = tid & 63, wave = tid >> 6;
  const int wr = wave >> 1, wc = wave & 1;
  const int l31 = lane & 31, lhi = lane >> 5;
  const int gtid = blockIdx.x * 256 + tid;
  const int gstride = gridDim.x << 8;

  f32x16 acc[2][2] = {};

  for (int k0 = 0; k0 < K; k0 += 64) {
#pragma unroll
    for (int it = 0; it < 4; ++it) {
      const int g = it * 256 + tid;
      const int row = g >> 3, ch = g & 7;
      const int src_ch = ch ^ (row & 7);  // inverse swizzle on SOURCE
      gload_lds16(A + (size_t)(bm + row) * K + k0 + src_ch * 8,
                  (char*)As + (it * 256 + wave * 64) * 16);
    }
#pragma unroll
    for (int it = 0; it < 4; ++it) {
      const int g = it * 256 + tid;
      const int row = g >> 3, ch = g & 7;
      const int src_ch = ch ^ (row & 7);
      gload_lds16(Bt + (size_t)(bn + row) * K + k0 + src_ch * 8,
                  (char*)Bs + (it * 256 + wave * 64) * 16);
    }
    __syncthreads();   // vmcnt(0) drain (staging + previous step's fill)

    // Piggybacked attn_out zero-fill: issued now, drains during compute.
    if (fill != nullptr) {
      const int step = k0 >> 6;
      f32x4 z = {0.f, 0.f, 0.f, 0.f};
#pragma unroll
      for (int j = 0; j < 3; ++j) {
        const int idx = gtid + (step * 3 + j) * gstride;
        if (idx < ATTN_V4)
          __builtin_nontemporal_store(z, (f32x4*)fill + idx);
      }
    }

#pragma unroll
    for (int kk = 0; kk < 4; ++kk) {   // 4 x K=16 sub-steps
      short8 a[2], b[2];
#pragma unroll
      for (int fi = 0; fi < 2; ++fi) {
        const int row = wr * 64 + fi * 32 + l31;
        const int ch = (kk * 2 + lhi) ^ (row & 7);  // swizzled read
        a[fi] = *(const short8*)((const char*)As + row * 128 + ch * 16);
      }
#pragma unroll
      for (int fj = 0; fj < 2; ++fj) {
        const int row = wc * 64 + fj * 32 + l31;
        const int ch = (kk * 2 + lhi) ^ (row & 7);
        b[fj] = *(const short8*)((const char*)Bs + row * 128 + ch * 16);
      }
#pragma unroll
      for (int fi = 0; fi < 2; ++fi)
#pragma unroll
        for (int fj = 0; fj < 2; ++fj)
          acc[fi][fj] = __builtin_amdgcn_mfma_f32_32x32x16_bf16(
              a[fi], b[fj], acc[fi][fj], 0, 0, 0);
    }
    __syncthreads();
  }

  // Epilogue staged through LDS (alias over As/Bs; safe after final barrier).
  // C/D layout: col = lane&31, row = (reg&3) + 8*(reg>>2) + 4*(lane>>5).
  if (OUT_BF16) {
    unsigned short (*Cs)[128] = (unsigned short (*)[128])smem;  // 32 KB
#pragma unroll
    for (int fj = 0; fj < 2; ++fj) {
      const float bv = bias[bn + wc * 64 + fj * 32 + l31];
      const int col = wc * 64 + fj * 32 + l31;
#pragma unroll
      for (int fi = 0; fi < 2; ++fi)
#pragma unroll
        for (int r = 0; r < 16; ++r) {
          const int row = wr * 64 + fi * 32 + (r & 3) + 8 * (r >> 2) + 4 * lhi;
          Cs[row][col] = f2bf(acc[fi][fj][r] + bv);
        }
    }
    __syncthreads();
    __hip_bfloat16* C = (__hip_bfloat16*)Cout;
#pragma unroll
    for (int t = 0; t < 8; ++t) {
      const int g = t * 256 + tid;      // 2048 x 16B chunks
      const int row = g >> 4, ch = g & 15;
      *(uint4*)(C + (size_t)(bm + row) * N + bn + ch * 8) =
          *(const uint4*)&Cs[row][ch * 8];
    }
  } else {
    float (*Cs)[128] = (float (*)[128])smem;  // 32 KB = 64 rows
    float* C = (float*)Cout;
#pragma unroll
    for (int half = 0; half < 2; ++half) {
      if (wr == half) {
#pragma unroll
        for (int fj = 0; fj < 2; ++fj) {
          const float bv = bias[bn + wc * 64 + fj * 32 + l31];
          const int col = wc * 64 + fj * 32 + l31;
#pragma unroll
          for (int fi = 0; fi < 2; ++fi)
#pragma unroll
            for (int r = 0; r < 16; ++r) {
              const int row = fi * 32 + (r & 3) + 8 * (r >> 2) + 4 * lhi;  // 0..63
              Cs[row][col] = acc[fi][fj][r] + bv;
            }
        }
      }
      __syncthreads();
#pragma unroll
      for (int t = 0; t < 8; ++t) {
        const int g = t * 256 + tid;    // 2048 x float4 chunks
        const int row = g >> 5, ch = g & 31;
        *(float4*)(C + (size_t)(bm + half * 64 + row) * N + bn + ch * 4) =
            *(const float4*)&Cs[row][ch * 4];
      }
      __syncthreads();
    }
  }
}

// ---------------------------------------------------------------------------
// Banded causal attention (band width LAG+1 = 11; off-band probs exactly 0).
// One block per row, XCD-AFFINE mapping: block blk (XCD = blk%8) handles row
// bi = (blk%8)*1024 + blk/8, so XCD x walks rows x*1024..x*1024+1023 in
// order. The 11 k/v rows a block reads were all produced on the SAME XCD by
// the QKV GEMM's swizzle and are re-read by the next ~10 blocks on that XCD
// -> band reads become XCD-L2-local instead of ~8x L3 amplification.
// attn_out pre-zeroed by the QKV GEMM; only band entries written here.
// ---------------------------------------------------------------------------
__global__ __launch_bounds__(256) void band_attn(
    const __hip_bfloat16* __restrict__ qkv, const float* __restrict__ decay_p,
    __hip_bfloat16* __restrict__ ctx, float* __restrict__ attn_out) {
  const int blk = blockIdx.x;
  const int bi = ((blk & 7) << 10) | (blk >> 3);   // XCD-affine row
  const int b = bi >> 11;
  const int i = bi & (SEQ - 1);
  const int tid = threadIdx.x;
  const int h = tid >> 5;
  const int lane = tid & 31;

  __shared__ float dlds[LAG + 1];
  __shared__ float att_h[NH][LAG + 2];

  if (tid <= LAG) {
    float p = decay_p[tid];
    float sp = fmaxf(p, 0.0f) + log1pf(expf(-fabsf(p)));  // stable softplus
    dlds[tid] = -logf(sp + 1e-8f);
  }
  __syncthreads();

  const int jlo = (i >= LAG) ? (i - LAG) : 0;
  const int nj = i - jlo + 1;

  const unsigned int qu = *(const unsigned int*)(
      (const unsigned short*)(qkv + (size_t)bi * NQKV + h * HD) + 2 * lane);
  const float q0 = bf2f((unsigned short)qu);
  const float q1 = bf2f((unsigned short)(qu >> 16));

  float s[LAG + 1];
#pragma unroll
  for (int jj = 0; jj <= LAG; jj++) {
    const int j = jlo + jj;
    const bool ok = (j <= i);
    const int jc = ok ? j : i;
    const unsigned int ku = *(const unsigned int*)(
        (const unsigned short*)(qkv + ((size_t)b * SEQ + jc) * NQKV + DM + h * HD) +
        2 * lane);
    float part = q0 * bf2f((unsigned short)ku) +
                 q1 * bf2f((unsigned short)(ku >> 16));
#pragma unroll
    for (int m = 16; m >= 1; m >>= 1) part += __shfl_xor(part, m, 32);
    s[jj] = ok ? (part * 0.125f + dlds[i - j]) : -1e30f;
  }

  float mx = -1e30f;
#pragma unroll
  for (int jj = 0; jj <= LAG; jj++) mx = fmaxf(mx, s[jj]);
  float sum = 0.0f;
#pragma unroll
  for (int jj = 0; jj <= LAG; jj++) { s[jj] = expf(s[jj] - mx); sum += s[jj]; }
  const float inv = 1.0f / sum;

  float c0 = 0.0f, c1 = 0.0f;
#pragma unroll
  for (int jj = 0; jj <= LAG; jj++) {
    const float p = s[jj] * inv;
    const int jc = (jlo + jj <= i) ? (jlo + jj) : i;
    const unsigned int vu = *(const unsigned int*)(
        (const unsigned short*)(qkv + ((size_t)b * SEQ + jc) * NQKV + 2 * DM + h * HD) +
        2 * lane);
    c0 += p * bf2f((unsigned short)vu);
    c1 += p * bf2f((unsigned short)(vu >> 16));
    if (lane == 0) att_h[h][jj] = p;
  }
  const unsigned int pk =
      ((unsigned int)f2bf(c1) << 16) | (unsigned int)f2bf(c0);
  *(unsigned int*)((unsigned short*)(ctx + (size_t)bi * DM + h * HD) + 2 * lane) = pk;
  __syncthreads();

  // band write only (row pre-zeroed by QKV GEMM's fill)
  if (tid < nj) {
    float a = 0.0f;
#pragma unroll
    for (int hh = 0; hh < NH; hh++) a += att_h[hh][tid];
    __builtin_nontemporal_store(a * (1.0f / NH),
                                attn_out + (size_t)bi * SEQ + jlo + tid);
  }
}

// ---------------------------------------------------------------------------
extern "C" void kernel_launch(void* const* d_in, const int* in_sizes, int n_in,
                              void* d_out, int out_size, void* d_ws, size_t ws_size,
                              hipStream_t stream) {
  const float* x   = (const float*)d_in[0];
  const float* Wq  = (const float*)d_in[1];
  const float* bq  = (const float*)d_in[2];
  const float* Wk  = (const float*)d_in[3];
  const float* bk  = (const float*)d_in[4];
  const float* Wv  = (const float*)d_in[5];
  const float* bv  = (const float*)d_in[6];
  const float* Wo  = (const float*)d_in[7];
  const float* bo  = (const float*)d_in[8];
  const float* dec = (const float*)d_in[9];

  float* out      = (float*)d_out;                 // [B,S,D]
  float* attn_out = out + OUT0_ELEMS;              // [B,S,S]

  // Workspace layout (16B-aligned), ~44 MB
  char* w = (char*)d_ws;
  __hip_bfloat16* xb    = (__hip_bfloat16*)w;  w += (size_t)MROWS * DM * 2;
  __hip_bfloat16* Wtqkv = (__hip_bfloat16*)w;  w += (size_t)NQKV * DM * 2;
  __hip_bfloat16* Wot   = (__hip_bfloat16*)w;  w += (size_t)DM * DM * 2;
  float*          bcat  = (float*)w;           w += (size_t)NQKV * 4;
  __hip_bfloat16* qkv   = (__hip_bfloat16*)w;  w += (size_t)MROWS * NQKV * 2;
  __hip_bfloat16* ctxb  = (__hip_bfloat16*)w;

  prep<<<3073, 256, 0, stream>>>(x, Wq, Wk, Wv, Wo, bq, bk, bv,
                                 xb, Wtqkv, Wot, bcat);

  // Fused QKV projection (+ piggybacked attn_out zero-fill)
  gemm_mfma<true><<<768, 256, 0, stream>>>(xb, Wtqkv, bcat, qkv,
                                           NQKV, DM, NQKV / 128, attn_out);

  band_attn<<<MROWS, 256, 0, stream>>>(qkv, dec, ctxb, attn_out);

  // Output projection: [8192,512] @ [512,512] -> f32 out
  gemm_mfma<false><<<256, 256, 0, stream>>>(ctxb, Wot, bo, out,
                                            DM, DM, DM / 128, nullptr);
}

// Round 11
// 80.326 us; speedup vs baseline: 1.1081x; 1.0076x over previous
//
#include <hip/hip_runtime.h>
#include <hip/hip_bf16.h>
#include <math.h>

// Problem constants (fixed by reference)
constexpr int Bsz = 4;
constexpr int SEQ = 2048;
constexpr int DM  = 512;
constexpr int NH  = 8;
constexpr int HD  = 64;      // DM / NH
constexpr int LAG = 10;      // MAX_LAG
constexpr int MROWS = Bsz * SEQ;                        // 8192
constexpr size_t OUT0_ELEMS = (size_t)Bsz * SEQ * DM;   // 4,194,304
constexpr int NQKV = 3 * DM;                            // 1536
constexpr int ATTN_V4 = Bsz * SEQ * SEQ / 4;            // 4,194,304 float4s

typedef __attribute__((ext_vector_type(8))) short short8;
typedef __attribute__((ext_vector_type(4))) float f32x4;
typedef __attribute__((ext_vector_type(16))) float f32x16;

__device__ __forceinline__ float bf2f(unsigned short u) {
  union { unsigned int i; float f; } x; x.i = (unsigned int)u << 16; return x.f;
}
__device__ __forceinline__ unsigned short f2bf(float f) {
  __hip_bfloat16 h = __float2bfloat16(f);
  return *(unsigned short*)&h;
}

// ---------------------------------------------------------------------------
// async global -> LDS, 16B per lane. LDS dest is wave-uniform base + lane*16.
// ---------------------------------------------------------------------------
__device__ __forceinline__ void gload_lds16(const void* g, void* l) {
  __builtin_amdgcn_global_load_lds(
      (const __attribute__((address_space(1))) unsigned int*)g,
      (__attribute__((address_space(3))) unsigned int*)l, 16, 0, 0);
}

// ---------------------------------------------------------------------------
// Fused prep: blocks [0,2048) cast x f32->bf16; [2048,3072) transpose+cast
// weights; block 3072 concatenates biases.
// ---------------------------------------------------------------------------
__global__ __launch_bounds__(256) void prep(
    const float* __restrict__ x, const float* __restrict__ Wq,
    const float* __restrict__ Wk, const float* __restrict__ Wv,
    const float* __restrict__ Wo, const float* __restrict__ bq,
    const float* __restrict__ bk, const float* __restrict__ bv,
    __hip_bfloat16* __restrict__ xb, __hip_bfloat16* __restrict__ Wtqkv,
    __hip_bfloat16* __restrict__ Wot, float* __restrict__ bcat) {
  __shared__ float t[32][33];
  const int blk = blockIdx.x;
  const int tid = threadIdx.x;
  if (blk < 2048) {
    // x cast, 8 elems/thread
    size_t i = ((size_t)blk * 256 + tid) * 8;
    float4 a = *(const float4*)(x + i);
    float4 b = *(const float4*)(x + i + 4);
    union { unsigned short h[8]; uint4 u; } pk;
    pk.h[0] = f2bf(a.x); pk.h[1] = f2bf(a.y); pk.h[2] = f2bf(a.z); pk.h[3] = f2bf(a.w);
    pk.h[4] = f2bf(b.x); pk.h[5] = f2bf(b.y); pk.h[6] = f2bf(b.z); pk.h[7] = f2bf(b.w);
    *(uint4*)(xb + i) = pk.u;
  } else if (blk < 3072) {
    const int zb = blk - 2048;
    const int z = zb >> 8, rem = zb & 255;
    const float* W = (z == 0) ? Wq : (z == 1) ? Wk : (z == 2) ? Wv : Wo;
    __hip_bfloat16* dst = (z < 3) ? (Wtqkv + (size_t)z * DM * DM) : Wot;
    const int n0 = (rem & 15) * 32, k0 = (rem >> 4) * 32;
    const int tx = tid & 31, ty = tid >> 5;
#pragma unroll
    for (int r = 0; r < 4; r++)
      t[ty + r * 8][tx] = W[(size_t)(k0 + ty + r * 8) * DM + n0 + tx];
    __syncthreads();
#pragma unroll
    for (int r = 0; r < 4; r++)
      dst[(size_t)(n0 + ty + r * 8) * DM + k0 + tx] =
          __float2bfloat16(t[tx][ty + r * 8]);
  } else {
    for (int i = tid; i < NQKV; i += 256)
      bcat[i] = (i < 512) ? bq[i] : (i < 1024) ? bk[i - 512] : bv[i - 1024];
  }
}

// ---------------------------------------------------------------------------
// QKV GEMM: qkv[8192,1536] = xb[8192,512] @ Wtqkv^T + bcat, bf16 out.
// 256x192 tile, BK=64, 8 waves (4M x 2N), 32x32x16 MFMA.
// T3-minimum stage-ahead double-buffer: STAGE(t+1) issued right after the
// barrier, before compute(t); __syncthreads()'s vmcnt(0) drain lands at the
// NEXT iteration's barrier, so load latency hides under ~1500 cyc of MFMA.
// Grid = 256 blocks = 1/CU (LDS 112 KB). XCD swizzle keeps M-row ownership
// identical to r9 (XCD x owns rows x*1024..+1023) for band_attn affinity.
// attn_out zero-fill piggybacked: exactly 4 f32x4/thread/K-step.
// FIX vs r10: epilogue store decomposition is 24 chunks/row (192 bf16 cols),
// was 12 -> wrote half-tiles and ran 256 rows past the tile (absmax 0.75).
// ---------------------------------------------------------------------------
__global__ __launch_bounds__(512) void qkv_gemm(
    const __hip_bfloat16* __restrict__ A, const __hip_bfloat16* __restrict__ Bt,
    const float* __restrict__ bias, __hip_bfloat16* __restrict__ C,
    float* __restrict__ fill) {
  __shared__ __align__(16) char smem[114688];   // 2 x (32K A + 24K B)

  // XCD-aware bijective swizzle (grid 256, 32 M-tiles x 8 N-tiles)
  int lin = blockIdx.x;
  lin = (lin & 7) * 32 + (lin >> 3);
  const int bm = (lin >> 3) * 256;
  const int bn = (lin & 7) * 192;

  const int tid = threadIdx.x;
  const int lane = tid & 63, wave = tid >> 6;
  const int wr = wave >> 1, wc = wave & 1;      // 4M x 2N wave grid
  const int l31 = lane & 31, lhi = lane >> 5;
  const int gtid = blockIdx.x * 512 + tid;      // for fill
  constexpr int GSTRIDE = 256 * 512;            // 131072

  f32x16 acc[2][3] = {};

  // ---- staging helper (A: 4 chunks, B: 3 chunks per thread) ----
  auto STAGE = [&](int buf, int k0) {
    char* base = smem + buf * 57344;
#pragma unroll
    for (int it = 0; it < 4; ++it) {
      const int g = it * 512 + tid;
      const int row = g >> 3, ch = g & 7;
      const int src_ch = ch ^ (row & 7);        // inverse swizzle on SOURCE
      gload_lds16(A + (size_t)(bm + row) * DM + k0 + src_ch * 8,
                  base + (it * 512 + wave * 64) * 16);
    }
    char* baseB = base + 32768;
#pragma unroll
    for (int it = 0; it < 3; ++it) {
      const int g = it * 512 + tid;
      const int row = g >> 3, ch = g & 7;
      const int src_ch = ch ^ (row & 7);
      gload_lds16(Bt + (size_t)(bn + row) * DM + k0 + src_ch * 8,
                  baseB + (it * 512 + wave * 64) * 16);
    }
  };

  STAGE(0, 0);  // prologue

  for (int t = 0; t < 8; ++t) {
    __syncthreads();              // drains stage(t) (+ previous fills)
    if (t < 7) STAGE((t + 1) & 1, (t + 1) * 64);

    // fill: 4 f32x4 per thread per step (256*512*8*4 = 4,194,304 exact)
    {
      f32x4 z = {0.f, 0.f, 0.f, 0.f};
#pragma unroll
      for (int j = 0; j < 4; ++j)
        __builtin_nontemporal_store(z, (f32x4*)fill + gtid + (t * 4 + j) * GSTRIDE);
    }

    const char* As = smem + (t & 1) * 57344;
    const char* Bs = As + 32768;
#pragma unroll
    for (int kk = 0; kk < 4; ++kk) {   // 4 x K=16 sub-steps
      short8 a[2], b[3];
#pragma unroll
      for (int fi = 0; fi < 2; ++fi) {
        const int row = wr * 64 + fi * 32 + l31;
        const int ch = (kk * 2 + lhi) ^ (row & 7);
        a[fi] = *(const short8*)(As + row * 128 + ch * 16);
      }
#pragma unroll
      for (int fj = 0; fj < 3; ++fj) {
        const int row = wc * 96 + fj * 32 + l31;
        const int ch = (kk * 2 + lhi) ^ (row & 7);
        b[fj] = *(const short8*)(Bs + row * 128 + ch * 16);
      }
#pragma unroll
      for (int fi = 0; fi < 2; ++fi)
#pragma unroll
        for (int fj = 0; fj < 3; ++fj)
          acc[fi][fj] = __builtin_amdgcn_mfma_f32_32x32x16_bf16(
              a[fi], b[fj], acc[fi][fj], 0, 0, 0);
    }
  }

  // ---- epilogue: stage C in LDS (96 KB bf16), store coalesced ----
  __syncthreads();
  unsigned short (*Cs)[192] = (unsigned short (*)[192])smem;
#pragma unroll
  for (int fj = 0; fj < 3; ++fj) {
    const int col = wc * 96 + fj * 32 + l31;
    const float bv = bias[bn + col];
#pragma unroll
    for (int fi = 0; fi < 2; ++fi)
#pragma unroll
      for (int r = 0; r < 16; ++r) {
        const int row = wr * 64 + fi * 32 + (r & 3) + 8 * (r >> 2) + 4 * lhi;
        Cs[row][col] = f2bf(acc[fi][fj][r] + bv);
      }
  }
  __syncthreads();
#pragma unroll
  for (int it = 0; it < 12; ++it) {
    const int g = it * 512 + tid;       // 6144 chunks of 8 bf16, 24 per row
    const int row = g / 24, ch = g % 24;
    *(uint4*)(C + (size_t)(bm + row) * NQKV + bn + ch * 8) =
        *(const uint4*)&Cs[row][ch * 8];
  }
}

// ---------------------------------------------------------------------------
// bf16 MFMA GEMM (r4 structure) -- used for the O projection.
// 128x128 tile, BK=64, 4 waves (2x2), 32x32x16 MFMA, m97 staging.
// ---------------------------------------------------------------------------
template <bool OUT_BF16>
__global__ __launch_bounds__(256) void gemm_mfma(
    const __hip_bfloat16* __restrict__ A, const __hip_bfloat16* __restrict__ Bt,
    const float* __restrict__ bias, void* __restrict__ Cout,
    int N, int K, int gx, float* __restrict__ fill) {
  __shared__ __align__(16) char smem[32768];
  unsigned short (*As)[64] = (unsigned short (*)[64])smem;            // [128][64]
  unsigned short (*Bs)[64] = (unsigned short (*)[64])(smem + 16384);  // [128][64]

  // XCD-aware bijective swizzle
  int lin = blockIdx.x;
  const int cpx = gridDim.x >> 3;
  lin = (lin & 7) * cpx + (lin >> 3);
  const int bm = (lin / gx) * 128;
  const int bn = (lin % gx) * 128;

  const int tid = threadIdx.x;
  const int lane = tid & 63, wave = tid >> 6;
  const int wr = wave >> 1, wc = wave & 1;
  const int l31 = lane & 31, lhi = lane >> 5;
  const int gtid = blockIdx.x * 256 + tid;
  const int gstride = gridDim.x << 8;

  f32x16 acc[2][2] = {};

  for (int k0 = 0; k0 < K; k0 += 64) {
#pragma unroll
    for (int it = 0; it < 4; ++it) {
      const int g = it * 256 + tid;
      const int row = g >> 3, ch = g & 7;
      const int src_ch = ch ^ (row & 7);  // inverse swizzle on SOURCE
      gload_lds16(A + (size_t)(bm + row) * K + k0 + src_ch * 8,
                  (char*)As + (it * 256 + wave * 64) * 16);
    }
#pragma unroll
    for (int it = 0; it < 4; ++it) {
      const int g = it * 256 + tid;
      const int row = g >> 3, ch = g & 7;
      const int src_ch = ch ^ (row & 7);
      gload_lds16(Bt + (size_t)(bn + row) * K + k0 + src_ch * 8,
                  (char*)Bs + (it * 256 + wave * 64) * 16);
    }
    __syncthreads();

    if (fill != nullptr) {
      const int step = k0 >> 6;
      f32x4 z = {0.f, 0.f, 0.f, 0.f};
#pragma unroll
      for (int j = 0; j < 3; ++j) {
        const int idx = gtid + (step * 3 + j) * gstride;
        if (idx < ATTN_V4)
          __builtin_nontemporal_store(z, (f32x4*)fill + idx);
      }
    }

#pragma unroll
    for (int kk = 0; kk < 4; ++kk) {
      short8 a[2], b[2];
#pragma unroll
      for (int fi = 0; fi < 2; ++fi) {
        const int row = wr * 64 + fi * 32 + l31;
        const int ch = (kk * 2 + lhi) ^ (row & 7);
        a[fi] = *(const short8*)((const char*)As + row * 128 + ch * 16);
      }
#pragma unroll
      for (int fj = 0; fj < 2; ++fj) {
        const int row = wc * 64 + fj * 32 + l31;
        const int ch = (kk * 2 + lhi) ^ (row & 7);
        b[fj] = *(const short8*)((const char*)Bs + row * 128 + ch * 16);
      }
#pragma unroll
      for (int fi = 0; fi < 2; ++fi)
#pragma unroll
        for (int fj = 0; fj < 2; ++fj)
          acc[fi][fj] = __builtin_amdgcn_mfma_f32_32x32x16_bf16(
              a[fi], b[fj], acc[fi][fj], 0, 0, 0);
    }
    __syncthreads();
  }

  // Epilogue staged through LDS.
  if (OUT_BF16) {
    unsigned short (*Cs)[128] = (unsigned short (*)[128])smem;
#pragma unroll
    for (int fj = 0; fj < 2; ++fj) {
      const float bv = bias[bn + wc * 64 + fj * 32 + l31];
      const int col = wc * 64 + fj * 32 + l31;
#pragma unroll
      for (int fi = 0; fi < 2; ++fi)
#pragma unroll
        for (int r = 0; r < 16; ++r) {
          const int row = wr * 64 + fi * 32 + (r & 3) + 8 * (r >> 2) + 4 * lhi;
          Cs[row][col] = f2bf(acc[fi][fj][r] + bv);
        }
    }
    __syncthreads();
    __hip_bfloat16* C = (__hip_bfloat16*)Cout;
#pragma unroll
    for (int t = 0; t < 8; ++t) {
      const int g = t * 256 + tid;
      const int row = g >> 4, ch = g & 15;
      *(uint4*)(C + (size_t)(bm + row) * N + bn + ch * 8) =
          *(const uint4*)&Cs[row][ch * 8];
    }
  } else {
    float (*Cs)[128] = (float (*)[128])smem;
    float* C = (float*)Cout;
#pragma unroll
    for (int half = 0; half < 2; ++half) {
      if (wr == half) {
#pragma unroll
        for (int fj = 0; fj < 2; ++fj) {
          const float bv = bias[bn + wc * 64 + fj * 32 + l31];
          const int col = wc * 64 + fj * 32 + l31;
#pragma unroll
          for (int fi = 0; fi < 2; ++fi)
#pragma unroll
            for (int r = 0; r < 16; ++r) {
              const int row = fi * 32 + (r & 3) + 8 * (r >> 2) + 4 * lhi;
              Cs[row][col] = acc[fi][fj][r] + bv;
            }
        }
      }
      __syncthreads();
#pragma unroll
      for (int t = 0; t < 8; ++t) {
        const int g = t * 256 + tid;
        const int row = g >> 5, ch = g & 31;
        *(float4*)(C + (size_t)(bm + half * 64 + row) * N + bn + ch * 4) =
            *(const float4*)&Cs[row][ch * 4];
      }
      __syncthreads();
    }
  }
}

// ---------------------------------------------------------------------------
// Banded causal attention, XCD-affine row mapping (r9, best measured).
// ---------------------------------------------------------------------------
__global__ __launch_bounds__(256) void band_attn(
    const __hip_bfloat16* __restrict__ qkv, const float* __restrict__ decay_p,
    __hip_bfloat16* __restrict__ ctx, float* __restrict__ attn_out) {
  const int blk = blockIdx.x;
  const int bi = ((blk & 7) << 10) | (blk >> 3);   // XCD-affine row
  const int b = bi >> 11;
  const int i = bi & (SEQ - 1);
  const int tid = threadIdx.x;
  const int h = tid >> 5;
  const int lane = tid & 31;

  __shared__ float dlds[LAG + 1];
  __shared__ float att_h[NH][LAG + 2];

  if (tid <= LAG) {
    float p = decay_p[tid];
    float sp = fmaxf(p, 0.0f) + log1pf(expf(-fabsf(p)));  // stable softplus
    dlds[tid] = -logf(sp + 1e-8f);
  }
  __syncthreads();

  const int jlo = (i >= LAG) ? (i - LAG) : 0;
  const int nj = i - jlo + 1;

  const unsigned int qu = *(const unsigned int*)(
      (const unsigned short*)(qkv + (size_t)bi * NQKV + h * HD) + 2 * lane);
  const float q0 = bf2f((unsigned short)qu);
  const float q1 = bf2f((unsigned short)(qu >> 16));

  float s[LAG + 1];
#pragma unroll
  for (int jj = 0; jj <= LAG; jj++) {
    const int j = jlo + jj;
    const bool ok = (j <= i);
    const int jc = ok ? j : i;
    const unsigned int ku = *(const unsigned int*)(
        (const unsigned short*)(qkv + ((size_t)b * SEQ + jc) * NQKV + DM + h * HD) +
        2 * lane);
    float part = q0 * bf2f((unsigned short)ku) +
                 q1 * bf2f((unsigned short)(ku >> 16));
#pragma unroll
    for (int m = 16; m >= 1; m >>= 1) part += __shfl_xor(part, m, 32);
    s[jj] = ok ? (part * 0.125f + dlds[i - j]) : -1e30f;
  }

  float mx = -1e30f;
#pragma unroll
  for (int jj = 0; jj <= LAG; jj++) mx = fmaxf(mx, s[jj]);
  float sum = 0.0f;
#pragma unroll
  for (int jj = 0; jj <= LAG; jj++) { s[jj] = expf(s[jj] - mx); sum += s[jj]; }
  const float inv = 1.0f / sum;

  float c0 = 0.0f, c1 = 0.0f;
#pragma unroll
  for (int jj = 0; jj <= LAG; jj++) {
    const float p = s[jj] * inv;
    const int jc = (jlo + jj <= i) ? (jlo + jj) : i;
    const unsigned int vu = *(const unsigned int*)(
        (const unsigned short*)(qkv + ((size_t)b * SEQ + jc) * NQKV + 2 * DM + h * HD) +
        2 * lane);
    c0 += p * bf2f((unsigned short)vu);
    c1 += p * bf2f((unsigned short)(vu >> 16));
    if (lane == 0) att_h[h][jj] = p;
  }
  const unsigned int pk =
      ((unsigned int)f2bf(c1) << 16) | (unsigned int)f2bf(c0);
  *(unsigned int*)((unsigned short*)(ctx + (size_t)bi * DM + h * HD) + 2 * lane) = pk;
  __syncthreads();

  // band write only (row pre-zeroed by QKV GEMM's fill)
  if (tid < nj) {
    float a = 0.0f;
#pragma unroll
    for (int hh = 0; hh < NH; hh++) a += att_h[hh][tid];
    __builtin_nontemporal_store(a * (1.0f / NH),
                                attn_out + (size_t)bi * SEQ + jlo + tid);
  }
}

// ---------------------------------------------------------------------------
extern "C" void kernel_launch(void* const* d_in, const int* in_sizes, int n_in,
                              void* d_out, int out_size, void* d_ws, size_t ws_size,
                              hipStream_t stream) {
  const float* x   = (const float*)d_in[0];
  const float* Wq  = (const float*)d_in[1];
  const float* bq  = (const float*)d_in[2];
  const float* Wk  = (const float*)d_in[3];
  const float* bk  = (const float*)d_in[4];
  const float* Wv  = (const float*)d_in[5];
  const float* bv  = (const float*)d_in[6];
  const float* Wo  = (const float*)d_in[7];
  const float* bo  = (const float*)d_in[8];
  const float* dec = (const float*)d_in[9];

  float* out      = (float*)d_out;                 // [B,S,D]
  float* attn_out = out + OUT0_ELEMS;              // [B,S,S]

  // Workspace layout (16B-aligned), ~44 MB
  char* w = (char*)d_ws;
  __hip_bfloat16* xb    = (__hip_bfloat16*)w;  w += (size_t)MROWS * DM * 2;
  __hip_bfloat16* Wtqkv = (__hip_bfloat16*)w;  w += (size_t)NQKV * DM * 2;
  __hip_bfloat16* Wot   = (__hip_bfloat16*)w;  w += (size_t)DM * DM * 2;
  float*          bcat  = (float*)w;           w += (size_t)NQKV * 4;
  __hip_bfloat16* qkv   = (__hip_bfloat16*)w;  w += (size_t)MROWS * NQKV * 2;
  __hip_bfloat16* ctxb  = (__hip_bfloat16*)w;

  prep<<<3073, 256, 0, stream>>>(x, Wq, Wk, Wv, Wo, bq, bk, bv,
                                 xb, Wtqkv, Wot, bcat);

  // Fused QKV projection (256x192 tile, dbuf stage-ahead, + attn_out fill)
  qkv_gemm<<<256, 512, 0, stream>>>(xb, Wtqkv, bcat, qkv, attn_out);

  band_attn<<<MROWS, 256, 0, stream>>>(qkv, dec, ctxb, attn_out);

  // Output projection: [8192,512] @ [512,512] -> f32 out
  gemm_mfma<false><<<256, 256, 0, stream>>>(ctxb, Wot, bo, out,
                                            DM, DM, DM / 128, nullptr);
}